// Round 3
// 153.747 us; speedup vs baseline: 1.0359x; 1.0359x over previous
//
#include <hip/hip_runtime.h>

#define H_ 160
#define W_ 160
#define HW_ (H_ * W_)
#define NPIX (8 * HW_)   // 204800 pixels

// ============================================================================
// R13: occupancy via LDS time-sharing, 100% R11-proven numerics.
// R12 (global weight frags + v_cvt_pk_bf16_f32) failed absmax 2.24 — could not
// localize (suspects: ws_size overflow of the new global region, or cvt_pk
// semantics). Reverted BOTH. Instead: wo (stage-1 weights) and wd (stage-2
// weights) are used in disjoint phases -> ONE shared 18.4KB LDS buffer,
// re-staged between stages with an extra barrier.
//   LDS 46.6KB -> 28.1KB  => 3 -> 5 blocks/CU (12 -> 20 waves/CU),
//   __launch_bounds__(256,5) (VGPR cap 102 >> 68 used).
// All data-path code (staging indices, pack2_bf16, MFMA layouts, bilinear
// combine, C-write) is verbatim R11.
// Layouts (verified m74/m101 + R9 pass): A[m=lane&31][k=(lane>>5)*8+j],
// B[n=lane&31][k=...], D: col n=lane&31, row=(reg&3)+8*(reg>>2)+4*(lane>>5).
// ============================================================================

typedef __attribute__((ext_vector_type(8)))  short  short8;   // 8 bf16
typedef __attribute__((ext_vector_type(4)))  float  f32x4;
typedef __attribute__((ext_vector_type(2)))  float  f32x2;
typedef __attribute__((ext_vector_type(16))) float  f32x16;
typedef __attribute__((ext_vector_type(4)))  unsigned u32x4;

__device__ __forceinline__ unsigned short bf16_rne(float f) {
    unsigned u = __float_as_uint(f);
    u += 0x7fffu + ((u >> 16) & 1u);
    return (unsigned short)(u >> 16);
}
__device__ __forceinline__ unsigned pack2_bf16(float a, float b) {
    unsigned ua = __float_as_uint(a); ua += 0x7fffu + ((ua >> 16) & 1u);
    unsigned ub = __float_as_uint(b); ub += 0x7fffu + ((ub >> 16) & 1u);
    return (ua >> 16) | (ub & 0xffff0000u);
}
__device__ __forceinline__ f32x2 up2(unsigned u) {
    f32x2 r;
    r.x = __uint_as_float(u << 16);
    r.y = __uint_as_float(u & 0xffff0000u);
    return r;
}

// ---- x (B,32,H,W) fp32 -> xT (B,H,W,32) bf16 (R11 verbatim) ----------------
__global__ __launch_bounds__(256) void nhwc_bf16(
    const float* __restrict__ x, unsigned short* __restrict__ xT)
{
    const int pix = blockIdx.x * 256 + threadIdx.x;
    const int p = pix % HW_;
    const int b = pix / HW_;
    const float* __restrict__ src = x + (size_t)b * 32 * HW_ + p;
    unsigned* __restrict__ dst = (unsigned*)(xT + (size_t)pix * 32);
    #pragma unroll
    for (int g = 0; g < 16; ++g)
        dst[g] = pack2_bf16(src[(2 * g) * HW_], src[(2 * g + 1) * HW_]);
}

// ---- fused: offset conv + bilinear sampling + dcn GEMM + ReLU --------------
__global__ __launch_bounds__(256, 5) void dcn_fused(
    const unsigned short* __restrict__ xT,   // (8,160,160,32) bf16
    const float* __restrict__ w_off,         // (18, 32, 3, 3)
    const float* __restrict__ b_off,         // (18,)
    const float* __restrict__ w_dcn,         // (32, 32, 3, 3)
    float* __restrict__ out)                 // (8, 32, 160, 160)
{
    // ONE weight-frag buffer, time-shared: wo in stage 1, wd in stage 2.
    __shared__ __align__(16) unsigned short wsh[9 * 2 * 64 * 8];  // 18,432 B
    __shared__ float offl[4 * 18 * 33];   // per-wave offset transpose, pad 33
    __shared__ float bl[32];
    const int tid = threadIdx.x;

    // stage wo (R11 staging loop, target = wsh)
    for (int d = tid; d < 9 * 1024; d += 256) {
        const int tap = d >> 10, r = d & 1023, j = r >> 5, c = r & 31;
        const int s = c >> 4, kg = (c >> 3) & 1;
        const int unit = (tap * 2 + s) * 64 + j + 32 * kg;
        wsh[unit * 8 + (c & 7)] = (j < 18) ? bf16_rne(w_off[(j * 32 + c) * 9 + tap])
                                           : (unsigned short)0;
    }
    if (tid < 32) bl[tid] = (tid < 18) ? b_off[tid] : 0.0f;
    __syncthreads();

    const int wave = tid >> 6, lane = tid & 63;
    const int n = lane & 31;          // pixel (A-row m) == out channel (D-col)
    const int hh = lane >> 5;         // k-group
    const int pixbase = blockIdx.x * 128 + wave * 32;
    const int pix = pixbase + n;
    const int w = pix % W_, h = (pix / W_) % H_, b = pix / HW_;
    const unsigned short* __restrict__ xb = xT + (size_t)b * HW_ * 32 + hh * 8;

    // ---------------- stage 1: offset conv GEMM (R9-verified) --------------
    {
        f32x16 acc = {};
        const u32x4 z4 = {0u, 0u, 0u, 0u};
        #pragma unroll
        for (int tap = 0; tap < 9; ++tap) {
            const int yy = h - 1 + tap / 3;
            const int xx = w - 1 + tap % 3;
            const bool valid = (yy >= 0) && (yy < H_) && (xx >= 0) && (xx < W_);
            const int idx = min(max(yy, 0), H_ - 1) * W_ + min(max(xx, 0), W_ - 1);
            const unsigned short* __restrict__ px_ = xb + (size_t)idx * 32;
            u32x4 l0 = *(const u32x4*)(px_);
            u32x4 l1 = *(const u32x4*)(px_ + 16);
            l0 = valid ? l0 : z4;
            l1 = valid ? l1 : z4;
            const short8 a0 = __builtin_bit_cast(short8, l0);
            const short8 a1 = __builtin_bit_cast(short8, l1);
            const short8 b0 = *(const short8*)(wsh + ((tap * 2 + 0) * 64 + lane) * 8);
            const short8 b1 = *(const short8*)(wsh + ((tap * 2 + 1) * 64 + lane) * 8);
            acc = __builtin_amdgcn_mfma_f32_32x32x16_bf16(a0, b0, acc, 0, 0, 0);
            acc = __builtin_amdgcn_mfma_f32_32x32x16_bf16(a1, b1, acc, 0, 0, 0);
        }
        // D-layout -> per-wave LDS transpose: [j(18)][pix(32)], row pad 33
        float* __restrict__ owp = offl + wave * 594;
        if (n < 18) {
            const float bia = bl[n];
            #pragma unroll
            for (int r = 0; r < 16; ++r) {
                const int prow = (r & 3) + 8 * (r >> 2) + 4 * hh;
                owp[n * 33 + prow] = acc[r] + bia;
            }
        }
    }
    __syncthreads();   // stage-1 reads of wsh done everywhere; offl visible

    // re-stage: wd into the SAME buffer
    for (int d = tid; d < 9 * 1024; d += 256) {
        const int tap = d >> 10, r = d & 1023, j = r >> 5, c = r & 31;
        const int s = c >> 4, kg = (c >> 3) & 1;
        const int unit = (tap * 2 + s) * 64 + j + 32 * kg;
        wsh[unit * 8 + (c & 7)] = bf16_rne(w_dcn[(j * 32 + c) * 9 + tap]);
    }
    __syncthreads();   // wd visible

    // ---------------- stage 2: bilinear sampling + dcn GEMM ----------------
    const float* __restrict__ ow = offl + wave * 594;
    f32x16 acc = {};

    #pragma unroll
    for (int tap = 0; tap < 9; ++tap) {
        const float dy = ow[(2 * tap) * 33 + n];
        const float dx = ow[(2 * tap + 1) * 33 + n];
        const float py = (float)(h - 1 + tap / 3) + dy;
        const float px = (float)(w - 1 + tap % 3) + dx;
        const float fy0 = floorf(py), fx0 = floorf(px);
        const float wy1 = py - fy0, wx1 = px - fx0;
        const float wy0 = 1.0f - wy1, wx0 = 1.0f - wx1;
        const int y0 = (int)fy0, x0 = (int)fx0;
        const bool vy0 = (y0 >= 0) && (y0 < H_);
        const bool vy1 = (y0 + 1 >= 0) && (y0 + 1 < H_);
        const bool vx0 = (x0 >= 0) && (x0 < W_);
        const bool vx1 = (x0 + 1 >= 0) && (x0 + 1 < W_);
        const float w00 = (vy0 && vx0) ? wy0 * wx0 : 0.0f;
        const float w01 = (vy0 && vx1) ? wy0 * wx1 : 0.0f;
        const float w10 = (vy1 && vx0) ? wy1 * wx0 : 0.0f;
        const float w11 = (vy1 && vx1) ? wy1 * wx1 : 0.0f;
        const int yc0 = min(max(y0, 0), H_ - 1), yc1 = min(max(y0 + 1, 0), H_ - 1);
        const int xc0 = min(max(x0, 0), W_ - 1), xc1 = min(max(x0 + 1, 0), W_ - 1);

        const unsigned short* __restrict__ pA = xb + (size_t)(yc0 * W_ + xc0) * 32;
        const unsigned short* __restrict__ pB = xb + (size_t)(yc0 * W_ + xc1) * 32;
        const unsigned short* __restrict__ pC = xb + (size_t)(yc1 * W_ + xc0) * 32;
        const unsigned short* __restrict__ pD = xb + (size_t)(yc1 * W_ + xc1) * 32;
        // 8 independent 16B gathers (2 k-steps x 4 corners)
        const u32x4 A0 = *(const u32x4*)(pA);      const u32x4 A1 = *(const u32x4*)(pA + 16);
        const u32x4 B0 = *(const u32x4*)(pB);      const u32x4 B1 = *(const u32x4*)(pB + 16);
        const u32x4 C0 = *(const u32x4*)(pC);      const u32x4 C1 = *(const u32x4*)(pC + 16);
        const u32x4 D0 = *(const u32x4*)(pD);      const u32x4 D1 = *(const u32x4*)(pD + 16);

        // R9-verified packed-fp32 bilinear combine
        #define COMB(a, bb, cc, dd) ({ \
            const f32x2 v = up2(a) * w00 + up2(bb) * w01 + up2(cc) * w10 + up2(dd) * w11; \
            pack2_bf16(v.x, v.y); })
        u32x4 av0, av1;
        av0.x = COMB(A0.x, B0.x, C0.x, D0.x);
        av0.y = COMB(A0.y, B0.y, C0.y, D0.y);
        av0.z = COMB(A0.z, B0.z, C0.z, D0.z);
        av0.w = COMB(A0.w, B0.w, C0.w, D0.w);
        av1.x = COMB(A1.x, B1.x, C1.x, D1.x);
        av1.y = COMB(A1.y, B1.y, C1.y, D1.y);
        av1.z = COMB(A1.z, B1.z, C1.z, D1.z);
        av1.w = COMB(A1.w, B1.w, C1.w, D1.w);
        #undef COMB

        const short8 a0 = __builtin_bit_cast(short8, av0);
        const short8 a1 = __builtin_bit_cast(short8, av1);
        const short8 b0 = *(const short8*)(wsh + ((tap * 2 + 0) * 64 + lane) * 8);
        const short8 b1 = *(const short8*)(wsh + ((tap * 2 + 1) * 64 + lane) * 8);
        acc = __builtin_amdgcn_mfma_f32_32x32x16_bf16(a0, b0, acc, 0, 0, 0);
        acc = __builtin_amdgcn_mfma_f32_32x32x16_bf16(a1, b1, acc, 0, 0, 0);
    }

    // D: col o = n; rows = pixels pixbase + g*8 + 4*hh + i
    float* __restrict__ ob = out + (size_t)b * 32 * HW_ + (size_t)n * HW_
                           + (pixbase - b * HW_) + 4 * hh;
    #pragma unroll
    for (int g = 0; g < 4; ++g) {
        f32x4 r;
        #pragma unroll
        for (int i = 0; i < 4; ++i) r[i] = fmaxf(acc[g * 4 + i], 0.0f);
        *(f32x4*)(ob + g * 8) = r;
    }
}

extern "C" void kernel_launch(void* const* d_in, const int* in_sizes, int n_in,
                              void* d_out, int out_size, void* d_ws, size_t ws_size,
                              hipStream_t stream) {
    const float* x     = (const float*)d_in[0];
    const float* w_off = (const float*)d_in[1];
    const float* b_off = (const float*)d_in[2];
    const float* w_dcn = (const float*)d_in[3];
    float* out = (float*)d_out;

    unsigned short* xT = (unsigned short*)d_ws;   // 13.1 MB bf16 NHWC (R11 footprint)

    nhwc_bf16<<<800, 256, 0, stream>>>(x, xT);
    dcn_fused<<<1600, 256, 0, stream>>>(xT, w_off, b_off, w_dcn, out);
}

// Round 4
// 147.953 us; speedup vs baseline: 1.0765x; 1.0392x over previous
//
#include <hip/hip_runtime.h>

#define H_ 160
#define W_ 160
#define HW_ (H_ * W_)
#define NPIX (8 * HW_)   // 204800 pixels

// ============================================================================
// R14: latency attack. R13 proved occupancy isn't the lever (3->5 blocks/CU
// gave only -5%): VGPR=48 means stage 2 runs tap-by-tap with ~9 exposed
// gather-latency bubbles per wave, and round-robin XCD dispatch makes
// neighbor-block halo sharing cross-L2 (FETCH 33MB vs 13.1MB input).
//  - stage 2: explicit depth-1 software pipeline (issue tap t+1's 8 gathers +
//    offset ds_reads before combining tap t; double-buffered named regs,
//    static indices under full unroll).
//  - __launch_bounds__(256,4): VGPR cap 128 for the pipeline (4 blocks/CU).
//  - XCD-chunked swizzle bid=(i%8)*200+i/8 (bijective, 1600%8==0): XCD k owns
//    batch k exactly (200 blocks = 25600 pix = one image, 1.6MB -> L2-resident).
// Numerics (staging indices, pack2_bf16, bilinear combine, MFMA layouts,
// C-write) verbatim R13/R11.
// Layouts (verified m74/m101 + R9 pass): A[m=lane&31][k=(lane>>5)*8+j],
// B[n=lane&31][k=...], D: col n=lane&31, row=(reg&3)+8*(reg>>2)+4*(lane>>5).
// ============================================================================

typedef __attribute__((ext_vector_type(8)))  short  short8;   // 8 bf16
typedef __attribute__((ext_vector_type(4)))  float  f32x4;
typedef __attribute__((ext_vector_type(2)))  float  f32x2;
typedef __attribute__((ext_vector_type(16))) float  f32x16;
typedef __attribute__((ext_vector_type(4)))  unsigned u32x4;

__device__ __forceinline__ unsigned short bf16_rne(float f) {
    unsigned u = __float_as_uint(f);
    u += 0x7fffu + ((u >> 16) & 1u);
    return (unsigned short)(u >> 16);
}
__device__ __forceinline__ unsigned pack2_bf16(float a, float b) {
    unsigned ua = __float_as_uint(a); ua += 0x7fffu + ((ua >> 16) & 1u);
    unsigned ub = __float_as_uint(b); ub += 0x7fffu + ((ub >> 16) & 1u);
    return (ua >> 16) | (ub & 0xffff0000u);
}
__device__ __forceinline__ f32x2 up2(unsigned u) {
    f32x2 r;
    r.x = __uint_as_float(u << 16);
    r.y = __uint_as_float(u & 0xffff0000u);
    return r;
}

// ---- x (B,32,H,W) fp32 -> xT (B,H,W,32) bf16 (R11 verbatim) ----------------
__global__ __launch_bounds__(256) void nhwc_bf16(
    const float* __restrict__ x, unsigned short* __restrict__ xT)
{
    const int pix = blockIdx.x * 256 + threadIdx.x;
    const int p = pix % HW_;
    const int b = pix / HW_;
    const float* __restrict__ src = x + (size_t)b * 32 * HW_ + p;
    unsigned* __restrict__ dst = (unsigned*)(xT + (size_t)pix * 32);
    #pragma unroll
    for (int g = 0; g < 16; ++g)
        dst[g] = pack2_bf16(src[(2 * g) * HW_], src[(2 * g + 1) * HW_]);
}

// ---- fused: offset conv + bilinear sampling + dcn GEMM + ReLU --------------
__global__ __launch_bounds__(256, 4) void dcn_fused(
    const unsigned short* __restrict__ xT,   // (8,160,160,32) bf16
    const float* __restrict__ w_off,         // (18, 32, 3, 3)
    const float* __restrict__ b_off,         // (18,)
    const float* __restrict__ w_dcn,         // (32, 32, 3, 3)
    float* __restrict__ out)                 // (8, 32, 160, 160)
{
    // ONE weight-frag buffer, time-shared: wo in stage 1, wd in stage 2.
    __shared__ __align__(16) unsigned short wsh[9 * 2 * 64 * 8];  // 18,432 B
    __shared__ float offl[4 * 18 * 33];   // per-wave offset transpose, pad 33
    __shared__ float bl[32];
    const int tid = threadIdx.x;

    // stage wo (R11 staging loop, target = wsh)
    for (int d = tid; d < 9 * 1024; d += 256) {
        const int tap = d >> 10, r = d & 1023, j = r >> 5, c = r & 31;
        const int s = c >> 4, kg = (c >> 3) & 1;
        const int unit = (tap * 2 + s) * 64 + j + 32 * kg;
        wsh[unit * 8 + (c & 7)] = (j < 18) ? bf16_rne(w_off[(j * 32 + c) * 9 + tap])
                                           : (unsigned short)0;
    }
    if (tid < 32) bl[tid] = (tid < 18) ? b_off[tid] : 0.0f;
    __syncthreads();

    const int wave = tid >> 6, lane = tid & 63;
    const int n = lane & 31;          // pixel (A-row m) == out channel (D-col)
    const int hh = lane >> 5;         // k-group
    // XCD-chunked swizzle: wg i -> bid, XCD i%8 owns batch i%8 (200 blocks
    // = one 160x160 image = 1.6MB xT -> L2-resident per XCD). Bijective.
    const int bid = (blockIdx.x & 7) * 200 + (blockIdx.x >> 3);
    const int pixbase = bid * 128 + wave * 32;
    const int pix = pixbase + n;
    const int w = pix % W_, h = (pix / W_) % H_, b = pix / HW_;
    const unsigned short* __restrict__ xb = xT + (size_t)b * HW_ * 32 + hh * 8;

    // ---------------- stage 1: offset conv GEMM (R9-verified) --------------
    {
        f32x16 acc = {};
        const u32x4 z4 = {0u, 0u, 0u, 0u};
        #pragma unroll
        for (int tap = 0; tap < 9; ++tap) {
            const int yy = h - 1 + tap / 3;
            const int xx = w - 1 + tap % 3;
            const bool valid = (yy >= 0) && (yy < H_) && (xx >= 0) && (xx < W_);
            const int idx = min(max(yy, 0), H_ - 1) * W_ + min(max(xx, 0), W_ - 1);
            const unsigned short* __restrict__ px_ = xb + (size_t)idx * 32;
            u32x4 l0 = *(const u32x4*)(px_);
            u32x4 l1 = *(const u32x4*)(px_ + 16);
            l0 = valid ? l0 : z4;
            l1 = valid ? l1 : z4;
            const short8 a0 = __builtin_bit_cast(short8, l0);
            const short8 a1 = __builtin_bit_cast(short8, l1);
            const short8 b0 = *(const short8*)(wsh + ((tap * 2 + 0) * 64 + lane) * 8);
            const short8 b1 = *(const short8*)(wsh + ((tap * 2 + 1) * 64 + lane) * 8);
            acc = __builtin_amdgcn_mfma_f32_32x32x16_bf16(a0, b0, acc, 0, 0, 0);
            acc = __builtin_amdgcn_mfma_f32_32x32x16_bf16(a1, b1, acc, 0, 0, 0);
        }
        // D-layout -> per-wave LDS transpose: [j(18)][pix(32)], row pad 33
        float* __restrict__ owp = offl + wave * 594;
        if (n < 18) {
            const float bia = bl[n];
            #pragma unroll
            for (int r = 0; r < 16; ++r) {
                const int prow = (r & 3) + 8 * (r >> 2) + 4 * hh;
                owp[n * 33 + prow] = acc[r] + bia;
            }
        }
    }
    __syncthreads();   // stage-1 reads of wsh done everywhere; offl visible

    // re-stage: wd into the SAME buffer
    for (int d = tid; d < 9 * 1024; d += 256) {
        const int tap = d >> 10, r = d & 1023, j = r >> 5, c = r & 31;
        const int s = c >> 4, kg = (c >> 3) & 1;
        const int unit = (tap * 2 + s) * 64 + j + 32 * kg;
        wsh[unit * 8 + (c & 7)] = bf16_rne(w_dcn[(j * 32 + c) * 9 + tap]);
    }
    __syncthreads();   // wd visible

    // ------ stage 2: bilinear sampling + dcn GEMM, depth-1 pipelined -------
    const float* __restrict__ ow = offl + wave * 594;
    f32x16 acc = {};

    // double-buffered pipeline state (indices static under full unroll)
    u32x4 gA0[2], gA1[2], gB0[2], gB1[2], gC0[2], gC1[2], gD0[2], gD1[2];
    f32x4 cw[2];   // {w00, w01, w10, w11}

    // PREP(t,s): offset ds_read + address math + issue the 8 gathers of tap t
    // into register set s. Math identical to R13's in-loop version.
    #define PREP(t, s) do { \
        const float dy = ow[(2 * (t)) * 33 + n]; \
        const float dx = ow[(2 * (t) + 1) * 33 + n]; \
        const float py = (float)(h - 1 + (t) / 3) + dy; \
        const float px = (float)(w - 1 + (t) % 3) + dx; \
        const float fy0 = floorf(py), fx0 = floorf(px); \
        const float wy1 = py - fy0, wx1 = px - fx0; \
        const float wy0 = 1.0f - wy1, wx0 = 1.0f - wx1; \
        const int y0 = (int)fy0, x0 = (int)fx0; \
        const bool vy0 = (y0 >= 0) && (y0 < H_); \
        const bool vy1 = (y0 + 1 >= 0) && (y0 + 1 < H_); \
        const bool vx0 = (x0 >= 0) && (x0 < W_); \
        const bool vx1 = (x0 + 1 >= 0) && (x0 + 1 < W_); \
        cw[s].x = (vy0 && vx0) ? wy0 * wx0 : 0.0f; \
        cw[s].y = (vy0 && vx1) ? wy0 * wx1 : 0.0f; \
        cw[s].z = (vy1 && vx0) ? wy1 * wx0 : 0.0f; \
        cw[s].w = (vy1 && vx1) ? wy1 * wx1 : 0.0f; \
        const int yc0 = min(max(y0, 0), H_ - 1), yc1 = min(max(y0 + 1, 0), H_ - 1); \
        const int xc0 = min(max(x0, 0), W_ - 1), xc1 = min(max(x0 + 1, 0), W_ - 1); \
        const unsigned short* pA = xb + (size_t)(yc0 * W_ + xc0) * 32; \
        const unsigned short* pB = xb + (size_t)(yc0 * W_ + xc1) * 32; \
        const unsigned short* pC = xb + (size_t)(yc1 * W_ + xc0) * 32; \
        const unsigned short* pD = xb + (size_t)(yc1 * W_ + xc1) * 32; \
        gA0[s] = *(const u32x4*)(pA);  gA1[s] = *(const u32x4*)(pA + 16); \
        gB0[s] = *(const u32x4*)(pB);  gB1[s] = *(const u32x4*)(pB + 16); \
        gC0[s] = *(const u32x4*)(pC);  gC1[s] = *(const u32x4*)(pC + 16); \
        gD0[s] = *(const u32x4*)(pD);  gD1[s] = *(const u32x4*)(pD + 16); \
    } while (0)

    PREP(0, 0);
    #pragma unroll
    for (int tap = 0; tap < 9; ++tap) {
        const int cur = tap & 1, nxt = cur ^ 1;
        if (tap < 8) PREP(tap + 1, nxt);   // hide next tap's gather latency

        const float w00 = cw[cur].x, w01 = cw[cur].y;
        const float w10 = cw[cur].z, w11 = cw[cur].w;
        // R9-verified packed-fp32 bilinear combine
        #define COMB(a, bb, cc, dd) ({ \
            const f32x2 v = up2(a) * w00 + up2(bb) * w01 + up2(cc) * w10 + up2(dd) * w11; \
            pack2_bf16(v.x, v.y); })
        u32x4 av0, av1;
        av0.x = COMB(gA0[cur].x, gB0[cur].x, gC0[cur].x, gD0[cur].x);
        av0.y = COMB(gA0[cur].y, gB0[cur].y, gC0[cur].y, gD0[cur].y);
        av0.z = COMB(gA0[cur].z, gB0[cur].z, gC0[cur].z, gD0[cur].z);
        av0.w = COMB(gA0[cur].w, gB0[cur].w, gC0[cur].w, gD0[cur].w);
        av1.x = COMB(gA1[cur].x, gB1[cur].x, gC1[cur].x, gD1[cur].x);
        av1.y = COMB(gA1[cur].y, gB1[cur].y, gC1[cur].y, gD1[cur].y);
        av1.z = COMB(gA1[cur].z, gB1[cur].z, gC1[cur].z, gD1[cur].z);
        av1.w = COMB(gA1[cur].w, gB1[cur].w, gC1[cur].w, gD1[cur].w);
        #undef COMB

        const short8 a0 = __builtin_bit_cast(short8, av0);
        const short8 a1 = __builtin_bit_cast(short8, av1);
        const short8 b0 = *(const short8*)(wsh + ((tap * 2 + 0) * 64 + lane) * 8);
        const short8 b1 = *(const short8*)(wsh + ((tap * 2 + 1) * 64 + lane) * 8);
        acc = __builtin_amdgcn_mfma_f32_32x32x16_bf16(a0, b0, acc, 0, 0, 0);
        acc = __builtin_amdgcn_mfma_f32_32x32x16_bf16(a1, b1, acc, 0, 0, 0);
    }
    #undef PREP

    // D: col o = n; rows = pixels pixbase + g*8 + 4*hh + i
    float* __restrict__ ob = out + (size_t)b * 32 * HW_ + (size_t)n * HW_
                           + (pixbase - b * HW_) + 4 * hh;
    #pragma unroll
    for (int g = 0; g < 4; ++g) {
        f32x4 r;
        #pragma unroll
        for (int i = 0; i < 4; ++i) r[i] = fmaxf(acc[g * 4 + i], 0.0f);
        *(f32x4*)(ob + g * 8) = r;
    }
}

extern "C" void kernel_launch(void* const* d_in, const int* in_sizes, int n_in,
                              void* d_out, int out_size, void* d_ws, size_t ws_size,
                              hipStream_t stream) {
    const float* x     = (const float*)d_in[0];
    const float* w_off = (const float*)d_in[1];
    const float* b_off = (const float*)d_in[2];
    const float* w_dcn = (const float*)d_in[3];
    float* out = (float*)d_out;

    unsigned short* xT = (unsigned short*)d_ws;   // 13.1 MB bf16 NHWC (R11 footprint)

    nhwc_bf16<<<800, 256, 0, stream>>>(x, xT);
    dcn_fused<<<1600, 256, 0, stream>>>(xT, w_off, b_off, w_dcn, out);
}